// Round 4
// baseline (655.277 us; speedup 1.0000x reference)
//
#include <hip/hip_runtime.h>
#include <hip/hip_bf16.h>

#define ALPHA_ (-30.0f)
#define EPS_ (1e-4f)
#define LOG2E_ (1.4426950408889634f)

typedef short bf16x8 __attribute__((ext_vector_type(8)));
typedef float f32x4 __attribute__((ext_vector_type(4)));
typedef float f32x2 __attribute__((ext_vector_type(2)));

__device__ __forceinline__ short f2bf(float f) {
  __hip_bfloat16 h = __float2bfloat16(f);
  return __builtin_bit_cast(short, h);
}

__device__ __forceinline__ bf16x8 ld_a(const short* p) {
  int2 lo = *reinterpret_cast<const int2*>(p);      // 8B aligned
  int2 hi = *reinterpret_cast<const int2*>(p + 4);
  union { int i[4]; bf16x8 v; } u;
  u.i[0] = lo.x; u.i[1] = lo.y; u.i[2] = hi.x; u.i[3] = hi.y;
  return u.v;
}

__device__ __forceinline__ bf16x8 ld_b(const short* p) {
  union { int4 i; bf16x8 v; } u;
  u.i = *reinterpret_cast<const int4*>(p);          // 16B aligned
  return u.v;
}

// LDS layout (bytes):
//   XC  @ 0     : 4 copies x 2192 bf16 (copy c: Cc[j] = bf16(x[j+c]))  = 17536
//   PS  @ 17536 : prefix sums of x^2, f32[2049] (+pad)                 =  8208
//   SH  @ 25744 : shapelets bf16 [64][L], scaled by -2*CE; later W     = 12288
//   SX  @ 38032 : CE*sumx2 f32[2048]                                   =  8192
//   S2  @ 46224 : CE*s2 f32[64]                                        =   256
//   RED @ 46480 : f32[512]                                             =  2048
//   FL  @ 48528 : features f32[192]                                    =   768
#define XC_OFF 0
#define PS_OFF 17536
#define SH_OFF 25744
#define SX_OFF 38032
#define S2_OFF 46224
#define RED_OFF 46480
#define FL_OFF 48528
#define SMEM_BYTES 49296
#define CL 2192

// 8 waves: wg = wv&3 (16-window group), sg = wv>>2 (32-shapelet half).
// Per wave: 16 windows x 32 shapelets; B fragments (KT x 2) register-resident.
template <int L, int SCALE>
__device__ __forceinline__ void scale_pass(const float* __restrict__ shp,
                                           char* smem, int tid, int lane,
                                           int wv, int col, int kg, int wg,
                                           int sg) {
  constexpr int T = 2048;
  constexpr int W = T - L + 1;
  constexpr int KT = L / 32;
  constexpr int NIT = (W + 63) / 64;   // total 64-window iters
  constexpr int M = W / 64;            // fully-valid iters (tail = NIT-M)
  constexpr float CE = ALPHA_ * LOG2E_ / (float)L;  // < 0
  constexpr float SCL = -2.0f * CE;

  short* xc = (short*)(smem + XC_OFF);
  float* ps = (float*)(smem + PS_OFF);
  short* sh = (short*)(smem + SH_OFF);
  float* sx = (float*)(smem + SX_OFF);
  float* s2 = (float*)(smem + S2_OFF);
  float* red = (float*)(smem + RED_OFF);
  float* fl = (float*)(smem + FL_OFF);

  __syncthreads();  // prior users of sh/sx/red done
  // stage shapelets (pre-scaled by -2*CE), sx = CE*sumx2, s2 partials
  for (int i = tid; i < 64 * L; i += 512) sh[i] = f2bf(shp[i] * SCL);
  for (int w = tid; w < 2048; w += 512)
    sx[w] = (w < W) ? CE * (ps[w + L] - ps[w]) : 0.f;
  {
    constexpr int LQ = L / 8;  // 8 threads per shapelet: k=lane, part=wv
    const float* sp = shp + lane * L + wv * LQ;
    float s = 0.f;
#pragma unroll
    for (int l = 0; l < LQ; ++l) s = fmaf(sp[l], sp[l], s);
    red[tid] = s;
  }
  __syncthreads();
  if (tid < 64) {
    float s = 0.f;
#pragma unroll
    for (int p = 0; p < 8; ++p) s += red[p * 64 + tid];
    s2[tid] = CE * s;
  }
  __syncthreads();

  // B fragments (register-resident: KT*2 frags <= 48 VGPR) + C-init values
  bf16x8 bfr[KT][2];
#pragma unroll
  for (int kt = 0; kt < KT; ++kt)
#pragma unroll
    for (int j = 0; j < 2; ++j)
      bfr[kt][j] = ld_b(sh + ((sg * 2 + j) * 16 + col) * L + kt * 32 + kg * 8);
  float s2c[2];
#pragma unroll
  for (int j = 0; j < 2; ++j) s2c[j] = s2[(sg * 2 + j) * 16 + col];

  const int cc = lane & 3;
  const short* ap = xc + cc * CL + (col - cc) + 8 * kg + wg * 16;
  const float* sp2 = sx + wg * 16 + kg * 4;

  f32x2 esP[2], dsP[2];
#pragma unroll
  for (int j = 0; j < 2; ++j) {
    esP[j] = (f32x2){0.f, 0.f};
    dsP[j] = (f32x2){0.f, 0.f};
  }

  int it = 0;
  for (; it < M; ++it) {  // fully-valid iterations: no masking
    f32x4 acc[2];
#pragma unroll
    for (int j = 0; j < 2; ++j)
      acc[j] = (f32x4){s2c[j], s2c[j], s2c[j], s2c[j]};
#pragma unroll
    for (int kt = 0; kt < KT; ++kt) {
      bf16x8 a = ld_a(ap + kt * 32);
#pragma unroll
      for (int j = 0; j < 2; ++j)
        acc[j] = __builtin_amdgcn_mfma_f32_16x16x32_bf16(a, bfr[kt][j],
                                                         acc[j], 0, 0, 0);
    }
    float4 sv = *reinterpret_cast<const float4*>(sp2);
    f32x2 sx01 = {sv.x, sv.y};
    f32x2 sx23 = {sv.z, sv.w};
#pragma unroll
    for (int j = 0; j < 2; ++j) {
      f32x2 u0 = (f32x2){acc[j][0], acc[j][1]} + sx01;  // u = alpha*log2e*d
      f32x2 u1 = (f32x2){acc[j][2], acc[j][3]} + sx23;
      f32x2 e0, e1;
      e0.x = __builtin_amdgcn_exp2f(u0.x);
      e0.y = __builtin_amdgcn_exp2f(u0.y);
      e1.x = __builtin_amdgcn_exp2f(u1.x);
      e1.y = __builtin_amdgcn_exp2f(u1.y);
      e0 += (f32x2){EPS_, EPS_};
      e1 += (f32x2){EPS_, EPS_};
      esP[j] += e0;
      esP[j] += e1;
      dsP[j] = __builtin_elementwise_fma(u0, e0, dsP[j]);
      dsP[j] = __builtin_elementwise_fma(u1, e1, dsP[j]);
    }
    ap += 64;
    sp2 += 64;
  }
  for (; it < NIT; ++it) {  // tail: per-element valid mask
    const int wb = it * 64 + wg * 16 + kg * 4;
    f32x4 acc[2];
#pragma unroll
    for (int j = 0; j < 2; ++j)
      acc[j] = (f32x4){s2c[j], s2c[j], s2c[j], s2c[j]};
#pragma unroll
    for (int kt = 0; kt < KT; ++kt) {
      bf16x8 a = ld_a(ap + kt * 32);
#pragma unroll
      for (int j = 0; j < 2; ++j)
        acc[j] = __builtin_amdgcn_mfma_f32_16x16x32_bf16(a, bfr[kt][j],
                                                         acc[j], 0, 0, 0);
    }
    float4 sv = *reinterpret_cast<const float4*>(sp2);
    const float svr[4] = {sv.x, sv.y, sv.z, sv.w};
#pragma unroll
    for (int j = 0; j < 2; ++j) {
#pragma unroll
      for (int r = 0; r < 4; ++r) {
        float u = acc[j][r] + svr[r];
        float e = __builtin_amdgcn_exp2f(u) + EPS_;
        float em = ((wb + r) < W) ? e : 0.f;
        esP[j].x += em;
        dsP[j].x = fmaf(u, em, dsP[j].x);
      }
    }
    ap += 64;
    sp2 += 64;
  }

  // reduce over kg groups (shfl) then over wg groups (LDS)
  constexpr float ALc = ALPHA_ * LOG2E_;
  float fe[2], fd[2];
#pragma unroll
  for (int j = 0; j < 2; ++j) {
    float es = esP[j].x + esP[j].y;
    float ds = dsP[j].x + dsP[j].y;
    es += __shfl_xor(es, 16, 64);
    es += __shfl_xor(es, 32, 64);
    ds += __shfl_xor(ds, 16, 64);
    ds += __shfl_xor(ds, 32, 64);
    fe[j] = es;
    fd[j] = ds;
  }
  if (lane < 16) {
#pragma unroll
    for (int j = 0; j < 2; ++j) {
      int slot = (wv * 2 + j) * 16 + lane;
      red[slot] = fe[j];
      red[256 + slot] = fd[j];
    }
  }
  __syncthreads();
  if (tid < 64) {
    const int nt = tid >> 4, c = tid & 15;
    const int sgg = nt >> 1, jj = nt & 1;
    float es = 0.f, ds = 0.f;
#pragma unroll
    for (int g = 0; g < 4; ++g) {
      int slot = ((sgg * 4 + g) * 2 + jj) * 16 + c;
      es += red[slot];
      ds += red[256 + slot];
    }
    fl[SCALE * 64 + tid] = ds / (es * ALc);  // = sum(d*e)/sum(e)
  }
}

__global__ void __launch_bounds__(512, 4)
feat_kernel(const float* __restrict__ series, const float* __restrict__ shp1,
            const float* __restrict__ shp2, const float* __restrict__ shp3,
            const float* __restrict__ Wm, const float* __restrict__ bvec,
            float* __restrict__ out) {
  __shared__ __align__(16) char smem[SMEM_BYTES];
  constexpr int T = 2048;

  short* xc = (short*)(smem + XC_OFF);
  float* ps = (float*)(smem + PS_OFF);
  float* red = (float*)(smem + RED_OFF);

  const int n = blockIdx.x;
  const int tid = threadIdx.x;
  const int lane = tid & 63;
  const int wv = tid >> 6;
  const int col = lane & 15;
  const int kg = lane >> 4;
  const int wg = wv & 3;
  const int sg = wv >> 2;

  // ---------- phase A (once): load row, scan x^2, 4 shifted bf16 copies ----
  const float* srow = series + (size_t)n * T;
  float4 v0 = *reinterpret_cast<const float4*>(srow + tid * 4);
  float xv[4] = {v0.x, v0.y, v0.z, v0.w};
  short bv8[8];
#pragma unroll
  for (int i = 0; i < 4; ++i) bv8[i] = f2bf(xv[i]);
  if (tid < 511) {  // next 4 elements for shifted copies (0 past row end)
    float4 v1 = *reinterpret_cast<const float4*>(srow + tid * 4 + 4);
    bv8[4] = f2bf(v1.x); bv8[5] = f2bf(v1.y);
    bv8[6] = f2bf(v1.z); bv8[7] = f2bf(v1.w);
  } else {
    bv8[4] = bv8[5] = bv8[6] = bv8[7] = 0;
  }

  float loc[4];
  float run = 0.f;
#pragma unroll
  for (int i = 0; i < 4; ++i) {
    run = fmaf(xv[i], xv[i], run);
    loc[i] = run;
  }
  // wave-level inclusive scan of per-thread sums
  float sc = run;
#pragma unroll
  for (int off = 1; off < 64; off <<= 1) {
    float t = __shfl_up(sc, off, 64);
    if (lane >= off) sc += t;
  }
  if (lane == 63) red[wv] = sc;
  __syncthreads();
  float wb0 = 0.f;
  for (int w = 0; w < wv; ++w) wb0 += red[w];
  float excl = wb0 + sc - run;
#pragma unroll
  for (int i = 0; i < 4; ++i) ps[tid * 4 + 1 + i] = excl + loc[i];
  if (tid == 0) ps[0] = 0.f;

#pragma unroll
  for (int c = 0; c < 4; ++c) {  // one ds_write_b64 per copy
    union { short s[4]; int2 q; } u;
#pragma unroll
    for (int i = 0; i < 4; ++i) u.s[i] = bv8[i + c];
    *reinterpret_cast<int2*>(xc + c * CL + tid * 4) = u.q;
  }
  if (tid < CL - 2048) {
    int j = 2048 + tid;
#pragma unroll
    for (int c = 0; c < 4; ++c) xc[c * CL + j] = 0;
  }
  // (scale_pass starts with __syncthreads())

  scale_pass<32, 0>(shp1, smem, tid, lane, wv, col, kg, wg, sg);
  scale_pass<64, 1>(shp2, smem, tid, lane, wv, col, kg, wg, sg);
  scale_pass<96, 2>(shp3, smem, tid, lane, wv, col, kg, wg, sg);

  // ---------- fused logits + softmax ----------
  __syncthreads();  // FL complete; SH region free
  float* wl = (float*)(smem + SH_OFF);
  const float* flp = (const float*)(smem + FL_OFF);
  for (int i = tid; i < 1920; i += 512) wl[i] = Wm[i];
  __syncthreads();
  float acc = 0.f;
  if (tid < 10) {
    acc = bvec[tid];
#pragma unroll 8
    for (int j = 0; j < 192; ++j) acc = fmaf(flp[j], wl[j * 10 + tid], acc);
    red[tid] = acc;
  }
  __syncthreads();
  if (tid < 10) {
    float m = red[0];
#pragma unroll
    for (int j = 1; j < 10; ++j) m = fmaxf(m, red[j]);
    float s = 0.f;
#pragma unroll
    for (int j = 0; j < 10; ++j)
      s += __builtin_amdgcn_exp2f((red[j] - m) * LOG2E_);
    out[(size_t)n * 10 + tid] = __builtin_amdgcn_exp2f((acc - m) * LOG2E_) / s;
  }
}

extern "C" void kernel_launch(void* const* d_in, const int* in_sizes, int n_in,
                              void* d_out, int out_size, void* d_ws, size_t ws_size,
                              hipStream_t stream) {
  const float* series = (const float*)d_in[0];  // [512, 2048]
  const float* shp1 = (const float*)d_in[1];    // [64, 32]
  const float* shp2 = (const float*)d_in[2];    // [64, 64]
  const float* shp3 = (const float*)d_in[3];    // [64, 96]
  const float* Wm = (const float*)d_in[4];      // [192, 10]
  const float* bv = (const float*)d_in[5];      // [10]
  float* out = (float*)d_out;                   // [512, 10] f32

  feat_kernel<<<512, 512, 0, stream>>>(series, shp1, shp2, shp3, Wm, bv, out);
}

// Round 5
// 642.651 us; speedup vs baseline: 1.0196x; 1.0196x over previous
//
#include <hip/hip_runtime.h>
#include <hip/hip_bf16.h>

#define ALPHA_ (-30.0f)
#define EPS_ (1e-4f)
#define LOG2E_ (1.4426950408889634f)

typedef short bf16x8 __attribute__((ext_vector_type(8)));
typedef float f32x4 __attribute__((ext_vector_type(4)));
typedef float f32x2 __attribute__((ext_vector_type(2)));

__device__ __forceinline__ short f2bf(float f) {
  __hip_bfloat16 h = __float2bfloat16(f);
  return __builtin_bit_cast(short, h);
}

__device__ __forceinline__ bf16x8 ld_a(const short* p) {
  int2 lo = *reinterpret_cast<const int2*>(p);      // 8B aligned
  int2 hi = *reinterpret_cast<const int2*>(p + 4);
  union { int i[4]; bf16x8 v; } u;
  u.i[0] = lo.x; u.i[1] = lo.y; u.i[2] = hi.x; u.i[3] = hi.y;
  return u.v;
}

__device__ __forceinline__ bf16x8 ld_b(const short* p) {
  union { int4 i; bf16x8 v; } u;
  u.i = *reinterpret_cast<const int4*>(p);          // 16B aligned
  return u.v;
}

// LDS layout (bytes), total 40784 -> rounds to 40960 = exactly 4 blocks/CU:
//   XC  @ 0     : 4 copies x 2136 bf16 (copy c: Cc[j] = bf16(x[j+c]))  = 17088
//   PS  @ 17088 : prefix sums of x^2, f32[2052]                        =  8208
//   SH  @ 25296 : this block's 32 shapelets bf16 [32][L], * -2*CE      =  6144
//   SX  @ 31440 : CE*sumx2 f32[2048]                                   =  8192
//   S2  @ 39632 : CE*s2 f32[32]                                        =   128
//   RED @ 39760 : f32[256]                                             =  1024
#define XC_OFF 0
#define PS_OFF 17088
#define SH_OFF 25296
#define SX_OFF 31440
#define S2_OFF 39632
#define RED_OFF 39760
#define SMEM_BYTES 40784
#define CL 2136

// Block = (row n, shapelet half sg0). 4 waves; wave wv handles window group
// wv*16 within each 64-window iter, all 32 shapelets of this block.
// B fragments: KT x 2 <= 6 frags = 24 VGPR, register-resident.
template <int L, int SCALE>
__device__ __forceinline__ void scale_pass(const float* __restrict__ shp,
                                           float* __restrict__ F, char* smem,
                                           int n, int sg0, int tid, int lane,
                                           int wv, int col, int kg) {
  constexpr int T = 2048;
  constexpr int W = T - L + 1;
  constexpr int KT = L / 32;
  constexpr int NIT = (W + 63) / 64;   // total 64-window iters
  constexpr int M = W / 64;            // fully-valid iters (tail = NIT-M)
  constexpr float CE = ALPHA_ * LOG2E_ / (float)L;  // < 0
  constexpr float SCL = -2.0f * CE;

  short* xc = (short*)(smem + XC_OFF);
  float* ps = (float*)(smem + PS_OFF);
  short* sh = (short*)(smem + SH_OFF);
  float* sx = (float*)(smem + SX_OFF);
  float* s2 = (float*)(smem + S2_OFF);
  float* red = (float*)(smem + RED_OFF);

  __syncthreads();  // prior users of sh/sx/red done
  // stage this block's 32 shapelets (pre-scaled by -2*CE), sx, s2 partials
  const float* shB = shp + sg0 * 32 * L;
  for (int i = tid; i < 32 * L; i += 256) sh[i] = f2bf(shB[i] * SCL);
  for (int w = tid; w < 2048; w += 256)
    sx[w] = (w < W) ? CE * (ps[w + L] - ps[w]) : 0.f;
  {
    constexpr int LQ = L / 8;  // 8 threads per shapelet
    const float* sp = shB + (tid & 31) * L + (tid >> 5) * LQ;
    float s = 0.f;
#pragma unroll
    for (int l = 0; l < LQ; ++l) s = fmaf(sp[l], sp[l], s);
    red[tid] = s;
  }
  __syncthreads();
  if (tid < 32) {
    float s = 0.f;
#pragma unroll
    for (int p = 0; p < 8; ++p) s += red[p * 32 + tid];
    s2[tid] = CE * s;
  }
  __syncthreads();

  // B fragments (register-resident) + per-lane C-init values
  bf16x8 bfr[KT][2];
#pragma unroll
  for (int kt = 0; kt < KT; ++kt)
#pragma unroll
    for (int j = 0; j < 2; ++j)
      bfr[kt][j] = ld_b(sh + (j * 16 + col) * L + kt * 32 + kg * 8);
  float s2c[2];
#pragma unroll
  for (int j = 0; j < 2; ++j) s2c[j] = s2[j * 16 + col];

  const int cc = lane & 3;
  const short* ap = xc + cc * CL + (col - cc) + 8 * kg + wv * 16;
  const float* sp2 = sx + wv * 16 + kg * 4;

  f32x2 esP[2], dsP[2];
#pragma unroll
  for (int j = 0; j < 2; ++j) {
    esP[j] = (f32x2){0.f, 0.f};
    dsP[j] = (f32x2){0.f, 0.f};
  }

  int it = 0;
  for (; it < M; ++it) {  // fully-valid iterations: no masking
    f32x4 acc[2];
#pragma unroll
    for (int j = 0; j < 2; ++j)
      acc[j] = (f32x4){s2c[j], s2c[j], s2c[j], s2c[j]};
#pragma unroll
    for (int kt = 0; kt < KT; ++kt) {
      bf16x8 a = ld_a(ap + kt * 32);
#pragma unroll
      for (int j = 0; j < 2; ++j)
        acc[j] = __builtin_amdgcn_mfma_f32_16x16x32_bf16(a, bfr[kt][j],
                                                         acc[j], 0, 0, 0);
    }
    float4 sv = *reinterpret_cast<const float4*>(sp2);
    f32x2 sx01 = {sv.x, sv.y};
    f32x2 sx23 = {sv.z, sv.w};
#pragma unroll
    for (int j = 0; j < 2; ++j) {
      f32x2 u0 = (f32x2){acc[j][0], acc[j][1]} + sx01;  // u = alpha*log2e*d
      f32x2 u1 = (f32x2){acc[j][2], acc[j][3]} + sx23;
      f32x2 e0, e1;
      e0.x = __builtin_amdgcn_exp2f(u0.x);
      e0.y = __builtin_amdgcn_exp2f(u0.y);
      e1.x = __builtin_amdgcn_exp2f(u1.x);
      e1.y = __builtin_amdgcn_exp2f(u1.y);
      e0 += (f32x2){EPS_, EPS_};
      e1 += (f32x2){EPS_, EPS_};
      esP[j] += e0;
      esP[j] += e1;
      dsP[j] = __builtin_elementwise_fma(u0, e0, dsP[j]);
      dsP[j] = __builtin_elementwise_fma(u1, e1, dsP[j]);
    }
    ap += 64;
    sp2 += 64;
  }
  for (; it < NIT; ++it) {  // tail: per-element valid mask
    const int wb = it * 64 + wv * 16 + kg * 4;
    f32x4 acc[2];
#pragma unroll
    for (int j = 0; j < 2; ++j)
      acc[j] = (f32x4){s2c[j], s2c[j], s2c[j], s2c[j]};
#pragma unroll
    for (int kt = 0; kt < KT; ++kt) {
      bf16x8 a = ld_a(ap + kt * 32);
#pragma unroll
      for (int j = 0; j < 2; ++j)
        acc[j] = __builtin_amdgcn_mfma_f32_16x16x32_bf16(a, bfr[kt][j],
                                                         acc[j], 0, 0, 0);
    }
    float4 sv = *reinterpret_cast<const float4*>(sp2);
    const float svr[4] = {sv.x, sv.y, sv.z, sv.w};
#pragma unroll
    for (int j = 0; j < 2; ++j) {
#pragma unroll
      for (int r = 0; r < 4; ++r) {
        float u = acc[j][r] + svr[r];
        float e = __builtin_amdgcn_exp2f(u) + EPS_;
        float em = ((wb + r) < W) ? e : 0.f;
        esP[j].x += em;
        dsP[j].x = fmaf(u, em, dsP[j].x);
      }
    }
    ap += 64;
    sp2 += 64;
  }

  // reduce over kg groups (shfl) then over waves (LDS)
  constexpr float ALc = ALPHA_ * LOG2E_;
  float fe[2], fd[2];
#pragma unroll
  for (int j = 0; j < 2; ++j) {
    float es = esP[j].x + esP[j].y;
    float ds = dsP[j].x + dsP[j].y;
    es += __shfl_xor(es, 16, 64);
    es += __shfl_xor(es, 32, 64);
    ds += __shfl_xor(ds, 16, 64);
    ds += __shfl_xor(ds, 32, 64);
    fe[j] = es;
    fd[j] = ds;
  }
  if (lane < 16) {
#pragma unroll
    for (int j = 0; j < 2; ++j) {
      int slot = (wv * 2 + j) * 16 + lane;
      red[slot] = fe[j];
      red[128 + slot] = fd[j];
    }
  }
  __syncthreads();
  if (tid < 32) {
    const int j = tid >> 4, c = tid & 15;
    float es = 0.f, ds = 0.f;
#pragma unroll
    for (int w = 0; w < 4; ++w) {
      int slot = (w * 2 + j) * 16 + c;
      es += red[slot];
      ds += red[128 + slot];
    }
    F[n * 192 + SCALE * 64 + sg0 * 32 + tid] = ds / (es * ALc);
  }
}

__global__ void __launch_bounds__(256, 4)
feat_kernel(const float* __restrict__ series, const float* __restrict__ shp1,
            const float* __restrict__ shp2, const float* __restrict__ shp3,
            float* __restrict__ F) {
  __shared__ __align__(16) char smem[SMEM_BYTES];
  constexpr int T = 2048;

  short* xc = (short*)(smem + XC_OFF);
  float* ps = (float*)(smem + PS_OFF);
  float* red = (float*)(smem + RED_OFF);

  const int n = blockIdx.x;
  const int sg0 = blockIdx.y;  // shapelet half
  const int tid = threadIdx.x;
  const int lane = tid & 63;
  const int wv = tid >> 6;
  const int col = lane & 15;
  const int kg = lane >> 4;

  // ---------- phase A: load row, scan x^2, 4 shifted bf16 copies ----------
  const float* srow = series + (size_t)n * T;
  float4 v0 = *reinterpret_cast<const float4*>(srow + tid * 8);
  float4 v1 = *reinterpret_cast<const float4*>(srow + tid * 8 + 4);
  float xv[8] = {v0.x, v0.y, v0.z, v0.w, v1.x, v1.y, v1.z, v1.w};
  short bv8[12];
#pragma unroll
  for (int i = 0; i < 8; ++i) bv8[i] = f2bf(xv[i]);
  if (tid < 255) {  // next 4 elements for shifted copies (0 past row end)
    float4 ve = *reinterpret_cast<const float4*>(srow + tid * 8 + 8);
    bv8[8] = f2bf(ve.x); bv8[9] = f2bf(ve.y);
    bv8[10] = f2bf(ve.z); bv8[11] = f2bf(ve.w);
  } else {
    bv8[8] = bv8[9] = bv8[10] = bv8[11] = 0;
  }

  float loc[8];
  float run = 0.f;
#pragma unroll
  for (int i = 0; i < 8; ++i) {
    run = fmaf(xv[i], xv[i], run);
    loc[i] = run;
  }
  // wave-level inclusive scan of per-thread sums
  float sc = run;
#pragma unroll
  for (int off = 1; off < 64; off <<= 1) {
    float t = __shfl_up(sc, off, 64);
    if (lane >= off) sc += t;
  }
  if (lane == 63) red[wv] = sc;
  __syncthreads();
  float wb0 = 0.f;
  for (int w = 0; w < wv; ++w) wb0 += red[w];
  float excl = wb0 + sc - run;
#pragma unroll
  for (int i = 0; i < 8; ++i) ps[tid * 8 + 1 + i] = excl + loc[i];
  if (tid == 0) ps[0] = 0.f;

#pragma unroll
  for (int c = 0; c < 4; ++c) {  // one ds_write_b128 per copy
    union { short s[8]; int4 q; } u;
#pragma unroll
    for (int i = 0; i < 8; ++i) u.s[i] = bv8[i + c];
    *reinterpret_cast<int4*>(xc + c * CL + tid * 8) = u.q;
  }
  if (tid < CL - 2048) {
    int j = 2048 + tid;
#pragma unroll
    for (int c = 0; c < 4; ++c) xc[c * CL + j] = 0;
  }
  // (scale_pass starts with __syncthreads())

  scale_pass<32, 0>(shp1, F, smem, n, sg0, tid, lane, wv, col, kg);
  scale_pass<64, 1>(shp2, F, smem, n, sg0, tid, lane, wv, col, kg);
  scale_pass<96, 2>(shp3, F, smem, n, sg0, tid, lane, wv, col, kg);
}

// ---------------------------------------------------------------------------
// Logits + softmax: out[n, :] = softmax(F[n, :] @ W + b)
// ---------------------------------------------------------------------------
__global__ void __launch_bounds__(256) logits_kernel(const float* __restrict__ F,
                                                     const float* __restrict__ Wm,
                                                     const float* __restrict__ bv,
                                                     float* __restrict__ out) {
  __shared__ float Ws[1920];
  __shared__ float bs[16];
  const int tid = threadIdx.x;
  for (int i = tid; i < 1920; i += 256) Ws[i] = Wm[i];
  if (tid < 10) bs[tid] = bv[tid];
  __syncthreads();

  const int n = blockIdx.x * 256 + tid;
  float acc[10];
#pragma unroll
  for (int c = 0; c < 10; ++c) acc[c] = bs[c];
  const float* f = F + n * 192;
  for (int j = 0; j < 192; j += 4) {
    float4 v = *reinterpret_cast<const float4*>(f + j);
#pragma unroll
    for (int c = 0; c < 10; ++c)
      acc[c] += v.x * Ws[(j + 0) * 10 + c] + v.y * Ws[(j + 1) * 10 + c] +
                v.z * Ws[(j + 2) * 10 + c] + v.w * Ws[(j + 3) * 10 + c];
  }
  float m = acc[0];
#pragma unroll
  for (int c = 1; c < 10; ++c) m = fmaxf(m, acc[c]);
  float s = 0.f;
  float e[10];
#pragma unroll
  for (int c = 0; c < 10; ++c) {
    e[c] = exp2f((acc[c] - m) * LOG2E_);
    s += e[c];
  }
  float inv = 1.f / s;
#pragma unroll
  for (int c = 0; c < 10; ++c) out[n * 10 + c] = e[c] * inv;
}

extern "C" void kernel_launch(void* const* d_in, const int* in_sizes, int n_in,
                              void* d_out, int out_size, void* d_ws, size_t ws_size,
                              hipStream_t stream) {
  const float* series = (const float*)d_in[0];  // [512, 2048]
  const float* shp1 = (const float*)d_in[1];    // [64, 32]
  const float* shp2 = (const float*)d_in[2];    // [64, 64]
  const float* shp3 = (const float*)d_in[3];    // [64, 96]
  const float* Wm = (const float*)d_in[4];      // [192, 10]
  const float* bv = (const float*)d_in[5];      // [10]
  float* out = (float*)d_out;                   // [512, 10] f32
  float* F = (float*)d_ws;                      // [512, 192] features

  feat_kernel<<<dim3(512, 2), 256, 0, stream>>>(series, shp1, shp2, shp3, F);
  logits_kernel<<<2, 256, 0, stream>>>(F, Wm, bv, out);
}

// Round 6
// 194.310 us; speedup vs baseline: 3.3723x; 3.3074x over previous
//
#include <hip/hip_runtime.h>
#include <hip/hip_bf16.h>

#define ALPHA_ (-30.0f)
#define EPS_ (1e-4f)
#define LOG2E_ (1.4426950408889634f)

typedef short bf16x8 __attribute__((ext_vector_type(8)));
typedef float f32x4 __attribute__((ext_vector_type(4)));
typedef float f32x2 __attribute__((ext_vector_type(2)));

__device__ __forceinline__ short f2bf(float f) {
  __hip_bfloat16 h = __float2bfloat16(f);
  return __builtin_bit_cast(short, h);
}

__device__ __forceinline__ bf16x8 ld_a(const short* p) {
  int2 lo = *reinterpret_cast<const int2*>(p);      // 8B aligned
  int2 hi = *reinterpret_cast<const int2*>(p + 4);
  union { int i[4]; bf16x8 v; } u;
  u.i[0] = lo.x; u.i[1] = lo.y; u.i[2] = hi.x; u.i[3] = hi.y;
  return u.v;
}

__device__ __forceinline__ bf16x8 ld_b(const short* p) {
  union { int4 i; bf16x8 v; } u;
  u.i = *reinterpret_cast<const int4*>(p);          // 16B aligned
  return u.v;
}

// LDS layout (bytes), total 40784 -> rounds to 40960 = exactly 4 blocks/CU:
//   XC  @ 0     : 4 copies x 2136 bf16 (copy c: Cc[j] = bf16(x[j+c]))  = 17088
//   PS  @ 17088 : prefix sums of x^2, f32[2052]                        =  8208
//   SH  @ 25296 : this block's 32 shapelets bf16 [32][L], * -2*CE      =  6144
//   SX  @ 31440 : CE*sumx2 f32[2048]                                   =  8192
//   S2  @ 39632 : CE*s2 f32[32]                                        =   128
//   RED @ 39760 : f32[256]                                             =  1024
#define XC_OFF 0
#define PS_OFF 17088
#define SH_OFF 25296
#define SX_OFF 31440
#define S2_OFF 39632
#define RED_OFF 39760
#define SMEM_BYTES 40784
#define CL 2136

// Block = (row n, shapelet half sg0). 4 waves; wave wv handles window group
// wv*16 within each 64-window iter, all 32 shapelets of this block.
// B fragments: KT x 2 <= 6 frags = 24 VGPR, register-resident.
// NOTE: __launch_bounds__(256, 2) — NOT 4. Empirically (R2/R4/R5) min-4-
// waves/EU caps the allocator at 64 arch VGPRs; this 3-pass kernel needs
// ~84 (R3) and spills catastrophically at 64 (1.3 GB scratch writes/dispatch).
// Occupancy comes from the 1024-block grid (4 blocks/CU via 40960B LDS).
template <int L, int SCALE>
__device__ __forceinline__ void scale_pass(const float* __restrict__ shp,
                                           float* __restrict__ F, char* smem,
                                           int n, int sg0, int tid, int lane,
                                           int wv, int col, int kg) {
  constexpr int T = 2048;
  constexpr int W = T - L + 1;
  constexpr int KT = L / 32;
  constexpr int NIT = (W + 63) / 64;   // total 64-window iters
  constexpr int M = W / 64;            // fully-valid iters (tail = NIT-M)
  constexpr float CE = ALPHA_ * LOG2E_ / (float)L;  // < 0
  constexpr float SCL = -2.0f * CE;

  short* xc = (short*)(smem + XC_OFF);
  float* ps = (float*)(smem + PS_OFF);
  short* sh = (short*)(smem + SH_OFF);
  float* sx = (float*)(smem + SX_OFF);
  float* s2 = (float*)(smem + S2_OFF);
  float* red = (float*)(smem + RED_OFF);

  __syncthreads();  // prior users of sh/sx/red done
  // stage this block's 32 shapelets (pre-scaled by -2*CE), sx, s2 partials
  const float* shB = shp + sg0 * 32 * L;
  for (int i = tid; i < 32 * L; i += 256) sh[i] = f2bf(shB[i] * SCL);
  for (int w = tid; w < 2048; w += 256)
    sx[w] = (w < W) ? CE * (ps[w + L] - ps[w]) : 0.f;
  {
    constexpr int LQ = L / 8;  // 8 threads per shapelet
    const float* sp = shB + (tid & 31) * L + (tid >> 5) * LQ;
    float s = 0.f;
#pragma unroll
    for (int l = 0; l < LQ; ++l) s = fmaf(sp[l], sp[l], s);
    red[tid] = s;
  }
  __syncthreads();
  if (tid < 32) {
    float s = 0.f;
#pragma unroll
    for (int p = 0; p < 8; ++p) s += red[p * 32 + tid];
    s2[tid] = CE * s;
  }
  __syncthreads();

  // B fragments (register-resident) + per-lane C-init values
  bf16x8 bfr[KT][2];
#pragma unroll
  for (int kt = 0; kt < KT; ++kt)
#pragma unroll
    for (int j = 0; j < 2; ++j)
      bfr[kt][j] = ld_b(sh + (j * 16 + col) * L + kt * 32 + kg * 8);
  float s2c[2];
#pragma unroll
  for (int j = 0; j < 2; ++j) s2c[j] = s2[j * 16 + col];

  const int cc = lane & 3;
  const short* ap = xc + cc * CL + (col - cc) + 8 * kg + wv * 16;
  const float* sp2 = sx + wv * 16 + kg * 4;

  f32x2 esP[2], dsP[2];
#pragma unroll
  for (int j = 0; j < 2; ++j) {
    esP[j] = (f32x2){0.f, 0.f};
    dsP[j] = (f32x2){0.f, 0.f};
  }

  int it = 0;
  for (; it < M; ++it) {  // fully-valid iterations: no masking
    f32x4 acc[2];
#pragma unroll
    for (int j = 0; j < 2; ++j)
      acc[j] = (f32x4){s2c[j], s2c[j], s2c[j], s2c[j]};
#pragma unroll
    for (int kt = 0; kt < KT; ++kt) {
      bf16x8 a = ld_a(ap + kt * 32);
#pragma unroll
      for (int j = 0; j < 2; ++j)
        acc[j] = __builtin_amdgcn_mfma_f32_16x16x32_bf16(a, bfr[kt][j],
                                                         acc[j], 0, 0, 0);
    }
    float4 sv = *reinterpret_cast<const float4*>(sp2);
    f32x2 sx01 = {sv.x, sv.y};
    f32x2 sx23 = {sv.z, sv.w};
#pragma unroll
    for (int j = 0; j < 2; ++j) {
      f32x2 u0 = (f32x2){acc[j][0], acc[j][1]} + sx01;  // u = alpha*log2e*d
      f32x2 u1 = (f32x2){acc[j][2], acc[j][3]} + sx23;
      f32x2 e0, e1;
      e0.x = __builtin_amdgcn_exp2f(u0.x);
      e0.y = __builtin_amdgcn_exp2f(u0.y);
      e1.x = __builtin_amdgcn_exp2f(u1.x);
      e1.y = __builtin_amdgcn_exp2f(u1.y);
      e0 += (f32x2){EPS_, EPS_};
      e1 += (f32x2){EPS_, EPS_};
      esP[j] += e0;
      esP[j] += e1;
      dsP[j] = __builtin_elementwise_fma(u0, e0, dsP[j]);
      dsP[j] = __builtin_elementwise_fma(u1, e1, dsP[j]);
    }
    ap += 64;
    sp2 += 64;
  }
  for (; it < NIT; ++it) {  // tail: per-element valid mask
    const int wb = it * 64 + wv * 16 + kg * 4;
    f32x4 acc[2];
#pragma unroll
    for (int j = 0; j < 2; ++j)
      acc[j] = (f32x4){s2c[j], s2c[j], s2c[j], s2c[j]};
#pragma unroll
    for (int kt = 0; kt < KT; ++kt) {
      bf16x8 a = ld_a(ap + kt * 32);
#pragma unroll
      for (int j = 0; j < 2; ++j)
        acc[j] = __builtin_amdgcn_mfma_f32_16x16x32_bf16(a, bfr[kt][j],
                                                         acc[j], 0, 0, 0);
    }
    float4 sv = *reinterpret_cast<const float4*>(sp2);
    const float svr[4] = {sv.x, sv.y, sv.z, sv.w};
#pragma unroll
    for (int j = 0; j < 2; ++j) {
#pragma unroll
      for (int r = 0; r < 4; ++r) {
        float u = acc[j][r] + svr[r];
        float e = __builtin_amdgcn_exp2f(u) + EPS_;
        float em = ((wb + r) < W) ? e : 0.f;
        esP[j].x += em;
        dsP[j].x = fmaf(u, em, dsP[j].x);
      }
    }
    ap += 64;
    sp2 += 64;
  }

  // reduce over kg groups (shfl) then over waves (LDS)
  constexpr float ALc = ALPHA_ * LOG2E_;
  float fe[2], fd[2];
#pragma unroll
  for (int j = 0; j < 2; ++j) {
    float es = esP[j].x + esP[j].y;
    float ds = dsP[j].x + dsP[j].y;
    es += __shfl_xor(es, 16, 64);
    es += __shfl_xor(es, 32, 64);
    ds += __shfl_xor(ds, 16, 64);
    ds += __shfl_xor(ds, 32, 64);
    fe[j] = es;
    fd[j] = ds;
  }
  if (lane < 16) {
#pragma unroll
    for (int j = 0; j < 2; ++j) {
      int slot = (wv * 2 + j) * 16 + lane;
      red[slot] = fe[j];
      red[128 + slot] = fd[j];
    }
  }
  __syncthreads();
  if (tid < 32) {
    const int j = tid >> 4, c = tid & 15;
    float es = 0.f, ds = 0.f;
#pragma unroll
    for (int w = 0; w < 4; ++w) {
      int slot = (w * 2 + j) * 16 + c;
      es += red[slot];
      ds += red[128 + slot];
    }
    F[n * 192 + SCALE * 64 + sg0 * 32 + tid] = ds / (es * ALc);
  }
}

__global__ void __launch_bounds__(256, 2)
feat_kernel(const float* __restrict__ series, const float* __restrict__ shp1,
            const float* __restrict__ shp2, const float* __restrict__ shp3,
            float* __restrict__ F) {
  __shared__ __align__(16) char smem[SMEM_BYTES];
  constexpr int T = 2048;

  short* xc = (short*)(smem + XC_OFF);
  float* ps = (float*)(smem + PS_OFF);
  float* red = (float*)(smem + RED_OFF);

  const int n = blockIdx.x;
  const int sg0 = blockIdx.y;  // shapelet half
  const int tid = threadIdx.x;
  const int lane = tid & 63;
  const int wv = tid >> 6;
  const int col = lane & 15;
  const int kg = lane >> 4;

  // ---------- phase A: load row, scan x^2, 4 shifted bf16 copies ----------
  const float* srow = series + (size_t)n * T;
  float4 v0 = *reinterpret_cast<const float4*>(srow + tid * 8);
  float4 v1 = *reinterpret_cast<const float4*>(srow + tid * 8 + 4);
  float xv[8] = {v0.x, v0.y, v0.z, v0.w, v1.x, v1.y, v1.z, v1.w};
  short bv8[12];
#pragma unroll
  for (int i = 0; i < 8; ++i) bv8[i] = f2bf(xv[i]);
  if (tid < 255) {  // next 4 elements for shifted copies (0 past row end)
    float4 ve = *reinterpret_cast<const float4*>(srow + tid * 8 + 8);
    bv8[8] = f2bf(ve.x); bv8[9] = f2bf(ve.y);
    bv8[10] = f2bf(ve.z); bv8[11] = f2bf(ve.w);
  } else {
    bv8[8] = bv8[9] = bv8[10] = bv8[11] = 0;
  }

  float loc[8];
  float run = 0.f;
#pragma unroll
  for (int i = 0; i < 8; ++i) {
    run = fmaf(xv[i], xv[i], run);
    loc[i] = run;
  }
  // wave-level inclusive scan of per-thread sums
  float sc = run;
#pragma unroll
  for (int off = 1; off < 64; off <<= 1) {
    float t = __shfl_up(sc, off, 64);
    if (lane >= off) sc += t;
  }
  if (lane == 63) red[wv] = sc;
  __syncthreads();
  float wb0 = 0.f;
  for (int w = 0; w < wv; ++w) wb0 += red[w];
  float excl = wb0 + sc - run;
#pragma unroll
  for (int i = 0; i < 8; ++i) ps[tid * 8 + 1 + i] = excl + loc[i];
  if (tid == 0) ps[0] = 0.f;

#pragma unroll
  for (int c = 0; c < 4; ++c) {  // one ds_write_b128 per copy
    union { short s[8]; int4 q; } u;
#pragma unroll
    for (int i = 0; i < 8; ++i) u.s[i] = bv8[i + c];
    *reinterpret_cast<int4*>(xc + c * CL + tid * 8) = u.q;
  }
  if (tid < CL - 2048) {
    int j = 2048 + tid;
#pragma unroll
    for (int c = 0; c < 4; ++c) xc[c * CL + j] = 0;
  }
  // (scale_pass starts with __syncthreads())

  scale_pass<32, 0>(shp1, F, smem, n, sg0, tid, lane, wv, col, kg);
  scale_pass<64, 1>(shp2, F, smem, n, sg0, tid, lane, wv, col, kg);
  scale_pass<96, 2>(shp3, F, smem, n, sg0, tid, lane, wv, col, kg);
}

// ---------------------------------------------------------------------------
// Logits + softmax: out[n, :] = softmax(F[n, :] @ W + b)
// ---------------------------------------------------------------------------
__global__ void __launch_bounds__(256) logits_kernel(const float* __restrict__ F,
                                                     const float* __restrict__ Wm,
                                                     const float* __restrict__ bv,
                                                     float* __restrict__ out) {
  __shared__ float Ws[1920];
  __shared__ float bs[16];
  const int tid = threadIdx.x;
  for (int i = tid; i < 1920; i += 256) Ws[i] = Wm[i];
  if (tid < 10) bs[tid] = bv[tid];
  __syncthreads();

  const int n = blockIdx.x * 256 + tid;
  float acc[10];
#pragma unroll
  for (int c = 0; c < 10; ++c) acc[c] = bs[c];
  const float* f = F + n * 192;
  for (int j = 0; j < 192; j += 4) {
    float4 v = *reinterpret_cast<const float4*>(f + j);
#pragma unroll
    for (int c = 0; c < 10; ++c)
      acc[c] += v.x * Ws[(j + 0) * 10 + c] + v.y * Ws[(j + 1) * 10 + c] +
                v.z * Ws[(j + 2) * 10 + c] + v.w * Ws[(j + 3) * 10 + c];
  }
  float m = acc[0];
#pragma unroll
  for (int c = 1; c < 10; ++c) m = fmaxf(m, acc[c]);
  float s = 0.f;
  float e[10];
#pragma unroll
  for (int c = 0; c < 10; ++c) {
    e[c] = exp2f((acc[c] - m) * LOG2E_);
    s += e[c];
  }
  float inv = 1.f / s;
#pragma unroll
  for (int c = 0; c < 10; ++c) out[n * 10 + c] = e[c] * inv;
}

extern "C" void kernel_launch(void* const* d_in, const int* in_sizes, int n_in,
                              void* d_out, int out_size, void* d_ws, size_t ws_size,
                              hipStream_t stream) {
  const float* series = (const float*)d_in[0];  // [512, 2048]
  const float* shp1 = (const float*)d_in[1];    // [64, 32]
  const float* shp2 = (const float*)d_in[2];    // [64, 64]
  const float* shp3 = (const float*)d_in[3];    // [64, 96]
  const float* Wm = (const float*)d_in[4];      // [192, 10]
  const float* bv = (const float*)d_in[5];      // [10]
  float* out = (float*)d_out;                   // [512, 10] f32
  float* F = (float*)d_ws;                      // [512, 192] features

  feat_kernel<<<dim3(512, 2), 256, 0, stream>>>(series, shp1, shp2, shp3, F);
  logits_kernel<<<2, 256, 0, stream>>>(F, Wm, bv, out);
}

// Round 7
// 57.985 us; speedup vs baseline: 11.3008x; 3.3510x over previous
//
#include <hip/hip_runtime.h>
#include <hip/hip_bf16.h>

#define ALPHA_ (-30.0f)
#define EPS_ (1e-4f)
#define LOG2E_ (1.4426950408889634f)

typedef short bf16x8 __attribute__((ext_vector_type(8)));
typedef float f32x4 __attribute__((ext_vector_type(4)));
typedef float f32x2 __attribute__((ext_vector_type(2)));

__device__ __forceinline__ short f2bf(float f) {
  __hip_bfloat16 h = __float2bfloat16(f);
  return __builtin_bit_cast(short, h);
}

__device__ __forceinline__ bf16x8 ld_a(const short* p) {
  int2 lo = *reinterpret_cast<const int2*>(p);      // 8B aligned
  int2 hi = *reinterpret_cast<const int2*>(p + 4);
  union { int i[4]; bf16x8 v; } u;
  u.i[0] = lo.x; u.i[1] = lo.y; u.i[2] = hi.x; u.i[3] = hi.y;
  return u.v;
}

__device__ __forceinline__ bf16x8 ld_b(const short* p) {
  union { int4 i; bf16x8 v; } u;
  u.i = *reinterpret_cast<const int4*>(p);          // 16B aligned
  return u.v;
}

// LDS layout (bytes), total 40352 -> 40448 block = 4 blocks/CU:
//   XC  @ 0     : 4 copies x 2192 bf16 (copy c: Cc[j] = bf16(x[j+c]))  = 17536
//   PS  @ 17536 : prefix sums of x^2, f32[2049]+pad                    =  8208
//   SH  @ 25744 : shapelets bf16 [64][L] * (-2*CE)  (phase A)         <= 12288
//   SX  @ 25744 : CE*sumx2 f32[2048]                (phase B, overlay) =  8192
//   S2  @ 38032 : CE*s2 f32[64]                                       =   256
//   RED @ 38288 : f32[512]                                            =  2048
#define XC_OFF 0
#define PS_OFF 17536
#define R2_OFF 25744
#define S2_OFF 38032
#define RED_OFF 38288
#define SMEM_BYTES 40352
#define CL 2192

// Block = (row n, scale). One template instantiation per block — the only
// shape that has never spilled (R2: 64 VGPR, 384 B scratch; the 3-pass
// inlined variants spilled 0.4-1.3 GB even at 128 VGPR).
// __launch_bounds__(256,3): cap ~168 VGPR so bfr[KT][4] (<=48) + acc stays
// register-resident (no LDS remat, no spill). Occupancy via LDS: 4 blocks/CU.
template <int L, int SCALE>
__device__ __forceinline__ void feat_impl(const float* __restrict__ series,
                                          const float* __restrict__ shp,
                                          float* __restrict__ F, char* smem) {
  constexpr int T = 2048;
  constexpr int W = T - L + 1;
  constexpr int KT = L / 32;
  constexpr int NIT = (W + 63) / 64;   // total 64-window iters
  constexpr int M = W / 64;            // fully-valid iters (tail = NIT-M)
  constexpr float CE = ALPHA_ * LOG2E_ / (float)L;  // < 0
  constexpr float SCL = -2.0f * CE;

  short* xc = (short*)(smem + XC_OFF);
  float* ps = (float*)(smem + PS_OFF);
  short* sh = (short*)(smem + R2_OFF);
  float* sx = (float*)(smem + R2_OFF);
  float* s2 = (float*)(smem + S2_OFF);
  float* red = (float*)(smem + RED_OFF);

  const int n = blockIdx.x;
  const int tid = threadIdx.x;
  const int lane = tid & 63;
  const int wv = tid >> 6;
  const int col = lane & 15;
  const int kg = lane >> 4;

  // ---------- phase A: load row, scan x^2, 4 shifted bf16 copies ----------
  const float* srow = series + (size_t)n * T;
  float4 v0 = *reinterpret_cast<const float4*>(srow + tid * 8);
  float4 v1 = *reinterpret_cast<const float4*>(srow + tid * 8 + 4);
  float xv[8] = {v0.x, v0.y, v0.z, v0.w, v1.x, v1.y, v1.z, v1.w};
  short bv8[12];
#pragma unroll
  for (int i = 0; i < 8; ++i) bv8[i] = f2bf(xv[i]);
  if (tid < 255) {  // next 4 elements for shifted copies (0 past row end)
    float4 ve = *reinterpret_cast<const float4*>(srow + tid * 8 + 8);
    bv8[8] = f2bf(ve.x); bv8[9] = f2bf(ve.y);
    bv8[10] = f2bf(ve.z); bv8[11] = f2bf(ve.w);
  } else {
    bv8[8] = bv8[9] = bv8[10] = bv8[11] = 0;
  }

  float loc[8];
  float run = 0.f;
#pragma unroll
  for (int i = 0; i < 8; ++i) {
    run = fmaf(xv[i], xv[i], run);
    loc[i] = run;
  }
  // wave-level inclusive scan of per-thread sums
  float sc = run;
#pragma unroll
  for (int off = 1; off < 64; off <<= 1) {
    float t = __shfl_up(sc, off, 64);
    if (lane >= off) sc += t;
  }
  if (lane == 63) red[wv] = sc;
  __syncthreads();
  float wb0 = 0.f;
  for (int w = 0; w < wv; ++w) wb0 += red[w];
  float excl = wb0 + sc - run;
#pragma unroll
  for (int i = 0; i < 8; ++i) ps[tid * 8 + 1 + i] = excl + loc[i];
  if (tid == 0) ps[0] = 0.f;

#pragma unroll
  for (int c = 0; c < 4; ++c) {  // one ds_write_b128 per copy
    union { short s[8]; int4 q; } u;
#pragma unroll
    for (int i = 0; i < 8; ++i) u.s[i] = bv8[i + c];
    *reinterpret_cast<int4*>(xc + c * CL + tid * 8) = u.q;
  }
  if (tid < CL - 2048) {
    int j = 2048 + tid;
#pragma unroll
    for (int c = 0; c < 4; ++c) xc[c * CL + j] = 0;
  }

  // stage shapelets (pre-scaled by -2*CE), vectorized; s2 quarter-partials
  {
    constexpr int NE = 64 * L;  // multiple of 1024
    for (int i4 = tid * 4; i4 < NE; i4 += 1024) {
      float4 v = *reinterpret_cast<const float4*>(shp + i4);
      union { short s[4]; int2 q; } u;
      u.s[0] = f2bf(v.x * SCL); u.s[1] = f2bf(v.y * SCL);
      u.s[2] = f2bf(v.z * SCL); u.s[3] = f2bf(v.w * SCL);
      *reinterpret_cast<int2*>(sh + i4) = u.q;
    }
  }
  {
    constexpr int LQ = L / 4;  // 4 threads per shapelet: k=lane, part=wv
    const float* sp = shp + lane * L + wv * LQ;
    float s = 0.f;
#pragma unroll
    for (int l = 0; l < LQ; ++l) s = fmaf(sp[l], sp[l], s);
    red[256 + tid] = s;  // red[0..3] still holds scan partials this phase
  }
  __syncthreads();
  if (tid < 64)
    s2[tid] = CE * (red[256 + tid] + red[320 + tid] + red[384 + tid] +
                    red[448 + tid]);
  __syncthreads();

  // ---------- B fragments + C-init to registers ----------
  bf16x8 bfr[KT][4];
#pragma unroll
  for (int kt = 0; kt < KT; ++kt)
#pragma unroll
    for (int nt = 0; nt < 4; ++nt)
      bfr[kt][nt] = ld_b(sh + (nt * 16 + col) * L + kt * 32 + kg * 8);
  float s2c[4];
#pragma unroll
  for (int nt = 0; nt < 4; ++nt) s2c[nt] = s2[nt * 16 + col];
  __syncthreads();

  // ---------- SX overlays SH ----------
  for (int w = tid; w < 2048; w += 256)
    sx[w] = (w < W) ? CE * (ps[w + L] - ps[w]) : 0.f;
  __syncthreads();

  // ---------- main loop (barrier-free) ----------
  const int cc = lane & 3;
  const short* ap = xc + cc * CL + (col - cc) + 8 * kg + wv * 16;
  const float* sp2 = sx + wv * 16 + kg * 4;

  f32x2 esP[4], dsP[4];
#pragma unroll
  for (int nt = 0; nt < 4; ++nt) {
    esP[nt] = (f32x2){0.f, 0.f};
    dsP[nt] = (f32x2){0.f, 0.f};
  }

  int it = 0;
  for (; it < M; ++it) {  // fully-valid iterations: no masking
    f32x4 acc[4];
#pragma unroll
    for (int nt = 0; nt < 4; ++nt)
      acc[nt] = (f32x4){s2c[nt], s2c[nt], s2c[nt], s2c[nt]};
#pragma unroll
    for (int kt = 0; kt < KT; ++kt) {
      bf16x8 a = ld_a(ap + kt * 32);
#pragma unroll
      for (int nt = 0; nt < 4; ++nt)
        acc[nt] = __builtin_amdgcn_mfma_f32_16x16x32_bf16(a, bfr[kt][nt],
                                                          acc[nt], 0, 0, 0);
    }
    float4 sv = *reinterpret_cast<const float4*>(sp2);
    f32x2 sx01 = {sv.x, sv.y};
    f32x2 sx23 = {sv.z, sv.w};
#pragma unroll
    for (int nt = 0; nt < 4; ++nt) {
      f32x2 u0 = (f32x2){acc[nt][0], acc[nt][1]} + sx01;  // u = a*log2e*d
      f32x2 u1 = (f32x2){acc[nt][2], acc[nt][3]} + sx23;
      f32x2 e0, e1;
      e0.x = __builtin_amdgcn_exp2f(u0.x);
      e0.y = __builtin_amdgcn_exp2f(u0.y);
      e1.x = __builtin_amdgcn_exp2f(u1.x);
      e1.y = __builtin_amdgcn_exp2f(u1.y);
      e0 += (f32x2){EPS_, EPS_};
      e1 += (f32x2){EPS_, EPS_};
      esP[nt] += e0;
      esP[nt] += e1;
      dsP[nt] = __builtin_elementwise_fma(u0, e0, dsP[nt]);
      dsP[nt] = __builtin_elementwise_fma(u1, e1, dsP[nt]);
    }
    ap += 64;
    sp2 += 64;
  }
  for (; it < NIT; ++it) {  // tail: per-element valid mask
    const int wb = it * 64 + wv * 16 + kg * 4;
    f32x4 acc[4];
#pragma unroll
    for (int nt = 0; nt < 4; ++nt)
      acc[nt] = (f32x4){s2c[nt], s2c[nt], s2c[nt], s2c[nt]};
#pragma unroll
    for (int kt = 0; kt < KT; ++kt) {
      bf16x8 a = ld_a(ap + kt * 32);
#pragma unroll
      for (int nt = 0; nt < 4; ++nt)
        acc[nt] = __builtin_amdgcn_mfma_f32_16x16x32_bf16(a, bfr[kt][nt],
                                                          acc[nt], 0, 0, 0);
    }
    float4 sv = *reinterpret_cast<const float4*>(sp2);
    const float svr[4] = {sv.x, sv.y, sv.z, sv.w};
#pragma unroll
    for (int nt = 0; nt < 4; ++nt) {
#pragma unroll
      for (int r = 0; r < 4; ++r) {
        float u = acc[nt][r] + svr[r];
        float e = __builtin_amdgcn_exp2f(u) + EPS_;
        float em = ((wb + r) < W) ? e : 0.f;
        esP[nt].x += em;
        dsP[nt].x = fmaf(u, em, dsP[nt].x);
      }
    }
    ap += 64;
    sp2 += 64;
  }

  // ---------- reduce: shfl over kg, LDS over waves ----------
  constexpr float ALc = ALPHA_ * LOG2E_;
  float fe[4], fd[4];
#pragma unroll
  for (int nt = 0; nt < 4; ++nt) {
    float es = esP[nt].x + esP[nt].y;
    float ds = dsP[nt].x + dsP[nt].y;
    es += __shfl_xor(es, 16, 64);
    es += __shfl_xor(es, 32, 64);
    ds += __shfl_xor(ds, 16, 64);
    ds += __shfl_xor(ds, 32, 64);
    fe[nt] = es;
    fd[nt] = ds;
  }
  __syncthreads();
  if (lane < 16) {
#pragma unroll
    for (int nt = 0; nt < 4; ++nt) {
      red[wv * 64 + nt * 16 + lane] = fe[nt];
      red[256 + wv * 64 + nt * 16 + lane] = fd[nt];
    }
  }
  __syncthreads();
  if (tid < 64) {
    float es = red[tid] + red[64 + tid] + red[128 + tid] + red[192 + tid];
    float ds = red[256 + tid] + red[320 + tid] + red[384 + tid] + red[448 + tid];
    F[n * 192 + SCALE * 64 + tid] = ds / (es * ALc);  // = sum(d*e)/sum(e)
  }
}

__global__ void __launch_bounds__(256, 3)
feat_kernel(const float* __restrict__ series, const float* __restrict__ shp1,
            const float* __restrict__ shp2, const float* __restrict__ shp3,
            float* __restrict__ F) {
  __shared__ __align__(16) char smem[SMEM_BYTES];
  if (blockIdx.y == 0)
    feat_impl<32, 0>(series, shp1, F, smem);
  else if (blockIdx.y == 1)
    feat_impl<64, 1>(series, shp2, F, smem);
  else
    feat_impl<96, 2>(series, shp3, F, smem);
}

// ---------------------------------------------------------------------------
// Logits + softmax: out[n, :] = softmax(F[n, :] @ W + b)
// ---------------------------------------------------------------------------
__global__ void __launch_bounds__(256) logits_kernel(const float* __restrict__ F,
                                                     const float* __restrict__ Wm,
                                                     const float* __restrict__ bv,
                                                     float* __restrict__ out) {
  __shared__ float Ws[1920];
  __shared__ float bs[16];
  const int tid = threadIdx.x;
  for (int i = tid; i < 1920; i += 256) Ws[i] = Wm[i];
  if (tid < 10) bs[tid] = bv[tid];
  __syncthreads();

  const int n = blockIdx.x * 256 + tid;
  float acc[10];
#pragma unroll
  for (int c = 0; c < 10; ++c) acc[c] = bs[c];
  const float* f = F + n * 192;
  for (int j = 0; j < 192; j += 4) {
    float4 v = *reinterpret_cast<const float4*>(f + j);
#pragma unroll
    for (int c = 0; c < 10; ++c)
      acc[c] += v.x * Ws[(j + 0) * 10 + c] + v.y * Ws[(j + 1) * 10 + c] +
                v.z * Ws[(j + 2) * 10 + c] + v.w * Ws[(j + 3) * 10 + c];
  }
  float m = acc[0];
#pragma unroll
  for (int c = 1; c < 10; ++c) m = fmaxf(m, acc[c]);
  float s = 0.f;
  float e[10];
#pragma unroll
  for (int c = 0; c < 10; ++c) {
    e[c] = exp2f((acc[c] - m) * LOG2E_);
    s += e[c];
  }
  float inv = 1.f / s;
#pragma unroll
  for (int c = 0; c < 10; ++c) out[n * 10 + c] = e[c] * inv;
}

extern "C" void kernel_launch(void* const* d_in, const int* in_sizes, int n_in,
                              void* d_out, int out_size, void* d_ws, size_t ws_size,
                              hipStream_t stream) {
  const float* series = (const float*)d_in[0];  // [512, 2048]
  const float* shp1 = (const float*)d_in[1];    // [64, 32]
  const float* shp2 = (const float*)d_in[2];    // [64, 64]
  const float* shp3 = (const float*)d_in[3];    // [64, 96]
  const float* Wm = (const float*)d_in[4];      // [192, 10]
  const float* bv = (const float*)d_in[5];      // [10]
  float* out = (float*)d_out;                   // [512, 10] f32
  float* F = (float*)d_ws;                      // [512, 192] features

  feat_kernel<<<dim3(512, 3), 256, 0, stream>>>(series, shp1, shp2, shp3, F);
  logits_kernel<<<2, 256, 0, stream>>>(F, Wm, bv, out);
}

// Round 8
// 57.524 us; speedup vs baseline: 11.3913x; 1.0080x over previous
//
#include <hip/hip_runtime.h>
#include <hip/hip_bf16.h>

#define ALPHA_ (-30.0f)
#define EPS_ (1e-4f)
#define LOG2E_ (1.4426950408889634f)

typedef short bf16x8 __attribute__((ext_vector_type(8)));
typedef float f32x4 __attribute__((ext_vector_type(4)));
typedef float f32x2 __attribute__((ext_vector_type(2)));

__device__ __forceinline__ short f2bf(float f) {
  __hip_bfloat16 h = __float2bfloat16(f);
  return __builtin_bit_cast(short, h);
}

__device__ __forceinline__ bf16x8 ld_a(const short* p) {
  int2 lo = *reinterpret_cast<const int2*>(p);      // 8B aligned
  int2 hi = *reinterpret_cast<const int2*>(p + 4);
  union { int i[4]; bf16x8 v; } u;
  u.i[0] = lo.x; u.i[1] = lo.y; u.i[2] = hi.x; u.i[3] = hi.y;
  return u.v;
}

__device__ __forceinline__ bf16x8 ld_b(const short* p) {
  union { int4 i; bf16x8 v; } u;
  u.i = *reinterpret_cast<const int4*>(p);          // 16B aligned
  return u.v;
}

// LDS layout (bytes), total 40352 -> 40448 block = 4 blocks/CU:
//   XC  @ 0     : 4 copies x 2192 bf16 (copy c: Cc[j] = bf16(x[j+c]))  = 17536
//   PS  @ 17536 : prefix sums of x^2, f32[2049]+pad                    =  8208
//   SH  @ 25744 : shapelets bf16 [64][L] * (-2*CE)  (phase A)         <= 12288
//   SX  @ 25744 : CE*sumx2 f32[2048]                (phase B, overlay) =  8192
//   S2  @ 38032 : CE*s2 f32[64]                                       =   256
//   RED @ 38288 : f32[512]                                            =  2048
#define XC_OFF 0
#define PS_OFF 17536
#define R2_OFF 25744
#define S2_OFF 38032
#define RED_OFF 38288
#define SMEM_BYTES 40352
#define CL 2192

// Block = (row n, scale). One template instantiation per block (never spills).
// amdgpu_waves_per_eu(2,4): occupancy is LDS-capped at 4 blocks/CU = 4
// waves/SIMD, so cap the allocator's occupancy TARGET at 4 -> 128-VGPR
// budget. Without it (R7) the backend targeted the 8-wave tier (64 VGPR)
// and rematerialized bfr from LDS every iteration (1.0M bank conflicts,
// MfmaUtil 20%). bfr(48)+acc(16)+esP/dsP(16)+misc ~ 110 must stay resident.
template <int L, int SCALE>
__device__ __forceinline__ void feat_impl(const float* __restrict__ series,
                                          const float* __restrict__ shp,
                                          float* __restrict__ F, char* smem) {
  constexpr int T = 2048;
  constexpr int W = T - L + 1;
  constexpr int KT = L / 32;
  constexpr int NIT = (W + 63) / 64;   // total 64-window iters
  constexpr int M = W / 64;            // fully-valid iters (tail = NIT-M)
  constexpr float CE = ALPHA_ * LOG2E_ / (float)L;  // < 0
  constexpr float SCL = -2.0f * CE;

  short* xc = (short*)(smem + XC_OFF);
  float* ps = (float*)(smem + PS_OFF);
  short* sh = (short*)(smem + R2_OFF);
  float* sx = (float*)(smem + R2_OFF);
  float* s2 = (float*)(smem + S2_OFF);
  float* red = (float*)(smem + RED_OFF);

  const int n = blockIdx.x;
  const int tid = threadIdx.x;
  const int lane = tid & 63;
  const int wv = tid >> 6;
  const int col = lane & 15;
  const int kg = lane >> 4;

  // ---------- phase A: load row, scan x^2, 4 shifted bf16 copies ----------
  const float* srow = series + (size_t)n * T;
  float4 v0 = *reinterpret_cast<const float4*>(srow + tid * 8);
  float4 v1 = *reinterpret_cast<const float4*>(srow + tid * 8 + 4);
  float xv[8] = {v0.x, v0.y, v0.z, v0.w, v1.x, v1.y, v1.z, v1.w};
  short bv8[12];
#pragma unroll
  for (int i = 0; i < 8; ++i) bv8[i] = f2bf(xv[i]);
  if (tid < 255) {  // next 4 elements for shifted copies (0 past row end)
    float4 ve = *reinterpret_cast<const float4*>(srow + tid * 8 + 8);
    bv8[8] = f2bf(ve.x); bv8[9] = f2bf(ve.y);
    bv8[10] = f2bf(ve.z); bv8[11] = f2bf(ve.w);
  } else {
    bv8[8] = bv8[9] = bv8[10] = bv8[11] = 0;
  }

  float loc[8];
  float run = 0.f;
#pragma unroll
  for (int i = 0; i < 8; ++i) {
    run = fmaf(xv[i], xv[i], run);
    loc[i] = run;
  }
  // wave-level inclusive scan of per-thread sums
  float sc = run;
#pragma unroll
  for (int off = 1; off < 64; off <<= 1) {
    float t = __shfl_up(sc, off, 64);
    if (lane >= off) sc += t;
  }
  if (lane == 63) red[wv] = sc;
  __syncthreads();
  float wb0 = 0.f;
  for (int w = 0; w < wv; ++w) wb0 += red[w];
  float excl = wb0 + sc - run;
#pragma unroll
  for (int i = 0; i < 8; ++i) ps[tid * 8 + 1 + i] = excl + loc[i];
  if (tid == 0) ps[0] = 0.f;

#pragma unroll
  for (int c = 0; c < 4; ++c) {  // one ds_write_b128 per copy
    union { short s[8]; int4 q; } u;
#pragma unroll
    for (int i = 0; i < 8; ++i) u.s[i] = bv8[i + c];
    *reinterpret_cast<int4*>(xc + c * CL + tid * 8) = u.q;
  }
  if (tid < CL - 2048) {
    int j = 2048 + tid;
#pragma unroll
    for (int c = 0; c < 4; ++c) xc[c * CL + j] = 0;
  }

  // stage shapelets (pre-scaled by -2*CE), vectorized; s2 quarter-partials
  {
    constexpr int NE = 64 * L;  // multiple of 1024
    for (int i4 = tid * 4; i4 < NE; i4 += 1024) {
      float4 v = *reinterpret_cast<const float4*>(shp + i4);
      union { short s[4]; int2 q; } u;
      u.s[0] = f2bf(v.x * SCL); u.s[1] = f2bf(v.y * SCL);
      u.s[2] = f2bf(v.z * SCL); u.s[3] = f2bf(v.w * SCL);
      *reinterpret_cast<int2*>(sh + i4) = u.q;
    }
  }
  {
    constexpr int LQ = L / 4;  // 4 threads per shapelet: k=lane, part=wv
    const float* sp = shp + lane * L + wv * LQ;
    float s = 0.f;
#pragma unroll
    for (int l = 0; l < LQ; ++l) s = fmaf(sp[l], sp[l], s);
    red[256 + tid] = s;  // red[0..3] still holds scan partials this phase
  }
  __syncthreads();
  if (tid < 64)
    s2[tid] = CE * (red[256 + tid] + red[320 + tid] + red[384 + tid] +
                    red[448 + tid]);
  __syncthreads();

  // ---------- B fragments + C-init to registers ----------
  bf16x8 bfr[KT][4];
#pragma unroll
  for (int kt = 0; kt < KT; ++kt)
#pragma unroll
    for (int nt = 0; nt < 4; ++nt)
      bfr[kt][nt] = ld_b(sh + (nt * 16 + col) * L + kt * 32 + kg * 8);
  float s2c[4];
#pragma unroll
  for (int nt = 0; nt < 4; ++nt) s2c[nt] = s2[nt * 16 + col];
  __syncthreads();

  // ---------- SX overlays SH ----------
  for (int w = tid; w < 2048; w += 256)
    sx[w] = (w < W) ? CE * (ps[w + L] - ps[w]) : 0.f;
  __syncthreads();

  // ---------- main loop (barrier-free) ----------
  const int cc = lane & 3;
  const short* ap = xc + cc * CL + (col - cc) + 8 * kg + wv * 16;
  const float* sp2 = sx + wv * 16 + kg * 4;

  f32x2 esP[4], dsP[4];
#pragma unroll
  for (int nt = 0; nt < 4; ++nt) {
    esP[nt] = (f32x2){0.f, 0.f};
    dsP[nt] = (f32x2){0.f, 0.f};
  }

  int it = 0;
  for (; it < M; ++it) {  // fully-valid iterations: no masking
    f32x4 acc[4];
#pragma unroll
    for (int nt = 0; nt < 4; ++nt)
      acc[nt] = (f32x4){s2c[nt], s2c[nt], s2c[nt], s2c[nt]};
#pragma unroll
    for (int kt = 0; kt < KT; ++kt) {
      bf16x8 a = ld_a(ap + kt * 32);
#pragma unroll
      for (int nt = 0; nt < 4; ++nt)
        acc[nt] = __builtin_amdgcn_mfma_f32_16x16x32_bf16(a, bfr[kt][nt],
                                                          acc[nt], 0, 0, 0);
    }
    float4 sv = *reinterpret_cast<const float4*>(sp2);
    f32x2 sx01 = {sv.x, sv.y};
    f32x2 sx23 = {sv.z, sv.w};
#pragma unroll
    for (int nt = 0; nt < 4; ++nt) {
      f32x2 u0 = (f32x2){acc[nt][0], acc[nt][1]} + sx01;  // u = a*log2e*d
      f32x2 u1 = (f32x2){acc[nt][2], acc[nt][3]} + sx23;
      f32x2 e0, e1;
      e0.x = __builtin_amdgcn_exp2f(u0.x);
      e0.y = __builtin_amdgcn_exp2f(u0.y);
      e1.x = __builtin_amdgcn_exp2f(u1.x);
      e1.y = __builtin_amdgcn_exp2f(u1.y);
      e0 += (f32x2){EPS_, EPS_};
      e1 += (f32x2){EPS_, EPS_};
      esP[nt] += e0;
      esP[nt] += e1;
      dsP[nt] = __builtin_elementwise_fma(u0, e0, dsP[nt]);
      dsP[nt] = __builtin_elementwise_fma(u1, e1, dsP[nt]);
    }
    ap += 64;
    sp2 += 64;
  }
  for (; it < NIT; ++it) {  // tail: per-element valid mask
    const int wb = it * 64 + wv * 16 + kg * 4;
    f32x4 acc[4];
#pragma unroll
    for (int nt = 0; nt < 4; ++nt)
      acc[nt] = (f32x4){s2c[nt], s2c[nt], s2c[nt], s2c[nt]};
#pragma unroll
    for (int kt = 0; kt < KT; ++kt) {
      bf16x8 a = ld_a(ap + kt * 32);
#pragma unroll
      for (int nt = 0; nt < 4; ++nt)
        acc[nt] = __builtin_amdgcn_mfma_f32_16x16x32_bf16(a, bfr[kt][nt],
                                                          acc[nt], 0, 0, 0);
    }
    float4 sv = *reinterpret_cast<const float4*>(sp2);
    const float svr[4] = {sv.x, sv.y, sv.z, sv.w};
#pragma unroll
    for (int nt = 0; nt < 4; ++nt) {
#pragma unroll
      for (int r = 0; r < 4; ++r) {
        float u = acc[nt][r] + svr[r];
        float e = __builtin_amdgcn_exp2f(u) + EPS_;
        float em = ((wb + r) < W) ? e : 0.f;
        esP[nt].x += em;
        dsP[nt].x = fmaf(u, em, dsP[nt].x);
      }
    }
    ap += 64;
    sp2 += 64;
  }

  // ---------- reduce: shfl over kg, LDS over waves ----------
  constexpr float ALc = ALPHA_ * LOG2E_;
  float fe[4], fd[4];
#pragma unroll
  for (int nt = 0; nt < 4; ++nt) {
    float es = esP[nt].x + esP[nt].y;
    float ds = dsP[nt].x + dsP[nt].y;
    es += __shfl_xor(es, 16, 64);
    es += __shfl_xor(es, 32, 64);
    ds += __shfl_xor(ds, 16, 64);
    ds += __shfl_xor(ds, 32, 64);
    fe[nt] = es;
    fd[nt] = ds;
  }
  __syncthreads();
  if (lane < 16) {
#pragma unroll
    for (int nt = 0; nt < 4; ++nt) {
      red[wv * 64 + nt * 16 + lane] = fe[nt];
      red[256 + wv * 64 + nt * 16 + lane] = fd[nt];
    }
  }
  __syncthreads();
  if (tid < 64) {
    float es = red[tid] + red[64 + tid] + red[128 + tid] + red[192 + tid];
    float ds = red[256 + tid] + red[320 + tid] + red[384 + tid] + red[448 + tid];
    F[n * 192 + SCALE * 64 + tid] = ds / (es * ALc);  // = sum(d*e)/sum(e)
  }
}

__global__ void __launch_bounds__(256)
    __attribute__((amdgpu_waves_per_eu(2, 4)))
feat_kernel(const float* __restrict__ series, const float* __restrict__ shp1,
            const float* __restrict__ shp2, const float* __restrict__ shp3,
            float* __restrict__ F) {
  __shared__ __align__(16) char smem[SMEM_BYTES];
  if (blockIdx.y == 0)
    feat_impl<32, 0>(series, shp1, F, smem);
  else if (blockIdx.y == 1)
    feat_impl<64, 1>(series, shp2, F, smem);
  else
    feat_impl<96, 2>(series, shp3, F, smem);
}

// ---------------------------------------------------------------------------
// Logits + softmax: out[n, :] = softmax(F[n, :] @ W + b)
// grid 8 x 64 threads (one thread per row) — spread the 393 KB F read over
// more CUs than the old 2x256 config.
// ---------------------------------------------------------------------------
__global__ void __launch_bounds__(64) logits_kernel(const float* __restrict__ F,
                                                    const float* __restrict__ Wm,
                                                    const float* __restrict__ bv,
                                                    float* __restrict__ out) {
  __shared__ float Ws[1920];
  __shared__ float bs[16];
  const int tid = threadIdx.x;
  for (int i = tid; i < 1920; i += 64) Ws[i] = Wm[i];
  if (tid < 10) bs[tid] = bv[tid];
  __syncthreads();

  const int n = blockIdx.x * 64 + tid;  // grid.x == 8 -> n in [0, 512)
  float acc[10];
#pragma unroll
  for (int c = 0; c < 10; ++c) acc[c] = bs[c];
  const float* f = F + n * 192;
  for (int j = 0; j < 192; j += 4) {
    float4 v = *reinterpret_cast<const float4*>(f + j);
#pragma unroll
    for (int c = 0; c < 10; ++c)
      acc[c] += v.x * Ws[(j + 0) * 10 + c] + v.y * Ws[(j + 1) * 10 + c] +
                v.z * Ws[(j + 2) * 10 + c] + v.w * Ws[(j + 3) * 10 + c];
  }
  float m = acc[0];
#pragma unroll
  for (int c = 1; c < 10; ++c) m = fmaxf(m, acc[c]);
  float s = 0.f;
  float e[10];
#pragma unroll
  for (int c = 0; c < 10; ++c) {
    e[c] = exp2f((acc[c] - m) * LOG2E_);
    s += e[c];
  }
  float inv = 1.f / s;
#pragma unroll
  for (int c = 0; c < 10; ++c) out[n * 10 + c] = e[c] * inv;
}

extern "C" void kernel_launch(void* const* d_in, const int* in_sizes, int n_in,
                              void* d_out, int out_size, void* d_ws, size_t ws_size,
                              hipStream_t stream) {
  const float* series = (const float*)d_in[0];  // [512, 2048]
  const float* shp1 = (const float*)d_in[1];    // [64, 32]
  const float* shp2 = (const float*)d_in[2];    // [64, 64]
  const float* shp3 = (const float*)d_in[3];    // [64, 96]
  const float* Wm = (const float*)d_in[4];      // [192, 10]
  const float* bv = (const float*)d_in[5];      // [10]
  float* out = (float*)d_out;                   // [512, 10] f32
  float* F = (float*)d_ws;                      // [512, 192] features

  feat_kernel<<<dim3(512, 3), 256, 0, stream>>>(series, shp1, shp2, shp3, F);
  logits_kernel<<<8, 64, 0, stream>>>(F, Wm, bv, out);
}